// Round 5
// baseline (226.032 us; speedup 1.0000x reference)
//
#include <hip/hip_runtime.h>
#include <hip/hip_bf16.h>
#include <hip/hip_fp16.h>

#define EPS 1e-5f
#define NE_ 100000
#define B_  256

typedef _Float16 half8 __attribute__((ext_vector_type(8)));
typedef float floatx16 __attribute__((ext_vector_type(16)));

// ws layout (fp32-element offsets):
//   x16  : fp16 A-layout [225 kc][2 hf][256 m][8]   @ 0       (460800 f32 slots)
//   b16  : fp16 B-layout [225 kc][2 hf][128 n][8]   @ 460800  (230400)
//   part : fp32 [5][256][128]                       @ 691200  (163840)
//   h16  : fp16 A-layout [14][256][8]               @ 855040  (14336)
#define WS_X16   0
#define WS_B16   460800
#define WS_PART  691200
#define WS_H16   855040

// =====================================================================
// Kernel 1: conv features -> x16 (fp16, MFMA-A chunk-major).
// grid 1024: sample b = bid>>2, channel-quarter q = bid&3 (25 ch each).
// =====================================================================
__global__ __launch_bounds__(256) void k_conv(
    const float* __restrict__ emb_e,
    const float* __restrict__ emb_rel,
    const float* __restrict__ bnr_g, const float* __restrict__ bnr_b,
    const float* __restrict__ bnr_m, const float* __restrict__ bnr_v,
    const float* __restrict__ bn0_g, const float* __restrict__ bn0_b,
    const float* __restrict__ bn0_m, const float* __restrict__ bn0_v,
    const float* __restrict__ bn1_g, const float* __restrict__ bn1_b,
    const float* __restrict__ bn1_m, const float* __restrict__ bn1_v,
    const int* __restrict__ e1, const int* __restrict__ rel,
    _Float16* __restrict__ x16)
{
    __shared__ float x0s[100];
    __shared__ float fs[625];

    const int bid = blockIdx.x;
    const int b = bid >> 2;
    const int q = bid & 3;
    const int t = threadIdx.x;
    const int ei = e1[b];
    const int ri = rel[b];

    if (t < 100) {
        float sc = bn0_g[0] * rsqrtf(bn0_v[0] + EPS);
        float sh = bn0_b[0] - bn0_m[0] * sc;
        x0s[t] = emb_e[(size_t)ei * 100 + t] * sc + sh;
    }
    for (int jj = t; jj < 625; jj += 256) {
        int j = q * 625 + jj;
        float sc = bnr_g[j] * rsqrtf(bnr_v[j] + EPS);
        fs[jj] = (emb_rel[(size_t)ri * 2500 + j] - bnr_m[j]) * sc + bnr_b[j];
    }
    __syncthreads();

    // 900 outputs: local channel cl=idx/36 (broadcast fs), p=idx%36
    for (int idx = t; idx < 900; idx += 256) {
        int cl = idx / 36;
        int p = idx - cl * 36;
        int c = q * 25 + cl;
        int hh = p / 6, ww = p - hh * 6;
        float sum = 0.f;
        #pragma unroll
        for (int ky = 0; ky < 5; ky++) {
            #pragma unroll
            for (int kx = 0; kx < 5; kx++) {
                sum += x0s[(hh + ky) * 10 + ww + kx] * fs[cl * 25 + ky * 5 + kx];
            }
        }
        float sc = bn1_g[c] * rsqrtf(bn1_v[c] + EPS);
        float y = fmaxf((sum - bn1_m[c]) * sc + bn1_b[c], 0.f);
        int k = c * 36 + p;
        x16[(((size_t)(k >> 3)) * 256 + b) * 8 + (k & 7)] = (_Float16)y;
    }
}

// =====================================================================
// Kernel 2: fc_w (fp32 [3600][100]) -> b16 (fp16 MFMA-B layout, 128-col pad)
// 460800 elements, grid 1800 x 256.
// =====================================================================
__global__ __launch_bounds__(256) void k_wprep(
    const float* __restrict__ fc_w,
    _Float16* __restrict__ b16)
{
    const int tid = blockIdx.x * 256 + threadIdx.x;   // [0, 460800)
    const int j  = tid & 7;
    const int n  = (tid >> 3) & 127;
    const int c8 = tid >> 10;                         // [0, 450)
    const int k  = c8 * 8 + j;
    float v = (n < 100) ? fc_w[(size_t)k * 100 + n] : 0.f;
    b16[tid] = (_Float16)v;
}

// =====================================================================
// Kernel 3: fc GEMM via f16 MFMA, split-K=5.
// grid (8 m-strips, 5 ks), block 256 = 4 waves = 4 n-strips (128 padded cols).
// part[ks][row][col] fp32.
// =====================================================================
__global__ __launch_bounds__(256) void k_fc(
    const _Float16* __restrict__ x16,
    const _Float16* __restrict__ b16,
    float* __restrict__ part)
{
    const int t    = threadIdx.x;
    const int wave = t >> 6;
    const int lane = t & 63;
    const int l31  = lane & 31;
    const int hf   = lane >> 5;

    const int mstrip = blockIdx.x;
    const int ks     = blockIdx.y;
    const int m      = mstrip * 32 + l31;
    const int nbase  = wave * 32;

    const half8* A  = (const half8*)x16;
    const half8* Bp = (const half8*)b16;

    floatx16 acc;
    #pragma unroll
    for (int r = 0; r < 16; r++) acc[r] = 0.f;

    const int kc0 = ks * 45;
    #pragma unroll 9
    for (int kk = 0; kk < 45; kk++) {
        const int c8 = (kc0 + kk) * 2 + hf;
        const half8 a = A[(size_t)c8 * 256 + m];
        const half8 b = Bp[(size_t)c8 * 128 + nbase + l31];
        acc = __builtin_amdgcn_mfma_f32_32x32x16_f16(a, b, acc, 0, 0, 0);
    }

    const int col = nbase + l31;
    float* pp = part + (size_t)ks * 32768;
    #pragma unroll
    for (int r = 0; r < 16; r++) {
        const int row = mstrip * 32 + (r & 3) + 8 * (r >> 2) + 4 * hf;
        pp[(size_t)row * 128 + col] = acc[r];
    }
}

// =====================================================================
// Kernel 4: reduce split-K + fc_b + BN2 + ReLU -> h16 (A-layout, pad 112)
// grid 100 x 256 (25600 = 256 m * 100 o)
// =====================================================================
__global__ __launch_bounds__(256) void k_hprep(
    const float* __restrict__ part,
    const float* __restrict__ fc_b,
    const float* __restrict__ bn2_g, const float* __restrict__ bn2_b,
    const float* __restrict__ bn2_m, const float* __restrict__ bn2_v,
    _Float16* __restrict__ h16)
{
    const int flat = blockIdx.x * 256 + threadIdx.x;   // m*100 + o
    const int m = flat / 100;
    const int o = flat - m * 100;
    float s = fc_b[o];
    #pragma unroll
    for (int ks = 0; ks < 5; ks++) s += part[(size_t)ks * 32768 + m * 128 + o];
    float sc = bn2_g[o] * rsqrtf(bn2_v[o] + EPS);
    float y = fmaxf((s - bn2_m[o]) * sc + bn2_b[o], 0.f);
    h16[((o >> 3) * 256 + m) * 8 + (o & 7)] = (_Float16)y;
    if (o < 12) {
        int kp = 100 + o;
        h16[((kp >> 3) * 256 + m) * 8 + (kp & 7)] = (_Float16)0.f;
    }
}

// =====================================================================
// Kernel 5: out[b][e] = sigmoid(h[b].emb_e[e] + bias[e]) via f16 MFMA.
// No LDS, no m-split: each wave does full m=256 (8 mt) x 32 n.
// grid = ceil(NE/128), block 256 (4 waves = 4 n-strips).
// =====================================================================
__global__ __launch_bounds__(256, 2) void k_scores(
    const float* __restrict__ emb_e,
    const float* __restrict__ bias,
    const _Float16* __restrict__ h16,
    float* __restrict__ out)
{
    const int t    = threadIdx.x;
    const int wave = t >> 6;
    const int lane = t & 63;
    const int l31  = lane & 31;
    const int hf   = lane >> 5;

    const int n0 = blockIdx.x * 128 + wave * 32;
    const int e  = n0 + l31;
    const int el = (e < NE_) ? e : (NE_ - 1);
    const float* erow = emb_e + (size_t)el * 100;

    // B-frags: k = kc*16 + hf*8 + j, zero-pad k >= 100
    half8 bf[7];
    #pragma unroll
    for (int kc = 0; kc < 7; kc++) {
        const int k0 = kc * 16 + hf * 8;
        half8 h;
        if (k0 + 8 <= 100) {
            const float4 f0 = *(const float4*)(erow + k0);
            const float4 f1 = *(const float4*)(erow + k0 + 4);
            h[0] = (_Float16)f0.x; h[1] = (_Float16)f0.y;
            h[2] = (_Float16)f0.z; h[3] = (_Float16)f0.w;
            h[4] = (_Float16)f1.x; h[5] = (_Float16)f1.y;
            h[6] = (_Float16)f1.z; h[7] = (_Float16)f1.w;
        } else if (k0 < 100) {   // k0 == 96
            const float4 f0 = *(const float4*)(erow + k0);
            h[0] = (_Float16)f0.x; h[1] = (_Float16)f0.y;
            h[2] = (_Float16)f0.z; h[3] = (_Float16)f0.w;
            h[4] = (_Float16)0.f; h[5] = (_Float16)0.f;
            h[6] = (_Float16)0.f; h[7] = (_Float16)0.f;
        } else {
            #pragma unroll
            for (int jj = 0; jj < 8; jj++) h[jj] = (_Float16)0.f;
        }
        bf[kc] = h;
    }

    const half8* hA = (const half8*)h16;
    const float bb = bias[el];

    floatx16 acc[8];
    #pragma unroll
    for (int mt = 0; mt < 8; mt++)
        #pragma unroll
        for (int r = 0; r < 16; r++) acc[mt][r] = 0.f;

    #pragma unroll
    for (int mt = 0; mt < 8; mt++) {
        const int m = mt * 32 + l31;
        #pragma unroll
        for (int kc = 0; kc < 7; kc++) {
            const half8 a = hA[(kc * 2 + hf) * 256 + m];
            acc[mt] = __builtin_amdgcn_mfma_f32_32x32x16_f16(a, bf[kc], acc[mt], 0, 0, 0);
        }
    }

    if (e < NE_) {
        #pragma unroll
        for (int mt = 0; mt < 8; mt++) {
            #pragma unroll
            for (int r = 0; r < 16; r++) {
                const int row = mt * 32 + (r & 3) + 8 * (r >> 2) + 4 * hf;
                out[(size_t)row * NE_ + e] = 1.f / (1.f + __expf(-(acc[mt][r] + bb)));
            }
        }
    }
}

extern "C" void kernel_launch(void* const* d_in, const int* in_sizes, int n_in,
                              void* d_out, int out_size, void* d_ws, size_t ws_size,
                              hipStream_t stream) {
    const float* emb_e   = (const float*)d_in[0];
    const float* emb_rel = (const float*)d_in[1];
    const float* bnr_g   = (const float*)d_in[2];
    const float* bnr_b   = (const float*)d_in[3];
    const float* bnr_m   = (const float*)d_in[4];
    const float* bnr_v   = (const float*)d_in[5];
    const float* bn0_g   = (const float*)d_in[6];
    const float* bn0_b   = (const float*)d_in[7];
    const float* bn0_m   = (const float*)d_in[8];
    const float* bn0_v   = (const float*)d_in[9];
    const float* bn1_g   = (const float*)d_in[10];
    const float* bn1_b   = (const float*)d_in[11];
    const float* bn1_m   = (const float*)d_in[12];
    const float* bn1_v   = (const float*)d_in[13];
    const float* fc_w    = (const float*)d_in[14];
    const float* fc_b    = (const float*)d_in[15];
    const float* bn2_g   = (const float*)d_in[16];
    const float* bn2_b   = (const float*)d_in[17];
    const float* bn2_m   = (const float*)d_in[18];
    const float* bn2_v   = (const float*)d_in[19];
    const float* bias    = (const float*)d_in[20];
    const int* e1  = (const int*)d_in[21];
    const int* rel = (const int*)d_in[22];

    float* ws = (float*)d_ws;
    _Float16* x16 = (_Float16*)(ws + WS_X16);
    _Float16* b16 = (_Float16*)(ws + WS_B16);
    float*    prt = ws + WS_PART;
    _Float16* h16 = (_Float16*)(ws + WS_H16);

    k_conv<<<dim3(1024), dim3(256), 0, stream>>>(
        emb_e, emb_rel,
        bnr_g, bnr_b, bnr_m, bnr_v,
        bn0_g, bn0_b, bn0_m, bn0_v,
        bn1_g, bn1_b, bn1_m, bn1_v,
        e1, rel, x16);

    k_wprep<<<dim3(1800), dim3(256), 0, stream>>>(fc_w, b16);

    k_fc<<<dim3(8, 5), dim3(256), 0, stream>>>(x16, b16, prt);

    k_hprep<<<dim3(100), dim3(256), 0, stream>>>(
        prt, fc_b, bn2_g, bn2_b, bn2_m, bn2_v, h16);

    k_scores<<<dim3((NE_ + 127) / 128), dim3(256), 0, stream>>>(
        emb_e, bias, h16, (float*)d_out);
}